// Round 17
// baseline (273.526 us; speedup 1.0000x reference)
//
#include <hip/hip_runtime.h>
#include <hip/hip_bf16.h>

// SingleHeadAttention: B=4, S=4096, D=1024, fp32 in/out, causal, interleaved RoPE.
// R15: pv -> BK=128 (full 32KB P-tile per barrier pair, 64 MFMA/step, 33 barrier
//      pairs instead of 66). Occupancy unaffected: pv is GRID-limited (512 blocks
//      = 2/CU); 64KB LDS keeps 2/CU. Bank-conflict-free by same XOR swizzle
//      (slotpos%8 bijective per 8-lane phase). Rest identical to R14 (280us).

#define SEQ 4096
#define DIM 1024

typedef short bf16x8 __attribute__((ext_vector_type(8)));
typedef float f32x4 __attribute__((ext_vector_type(4)));
typedef int i32x4 __attribute__((ext_vector_type(4)));

__device__ __forceinline__ unsigned short f2bf(float f) {
  unsigned int u = __float_as_uint(f);
  u += 0x7FFFu + ((u >> 16) & 1u);   // RNE
  return (unsigned short)(u >> 16);
}

// bijective XCD swizzle (grids % 8 == 0)
__device__ __forceinline__ int xcd_swz(int bid, int nwg) {
  return (bid & 7) * (nwg >> 3) + (bid >> 3);
}

__device__ __forceinline__ void gll16(const void* g, void* l) {
  __builtin_amdgcn_global_load_lds(
      (const __attribute__((address_space(1))) void*)g,
      (__attribute__((address_space(3))) void*)l, 16, 0, 0);
}

// fp32 -> bf16 for x and wq|wk|wv, plus lbuf zero-fill (one dispatch)
__global__ __launch_bounds__(256) void cvt_all_kernel(
    const float* __restrict__ x, const float* __restrict__ wq,
    const float* __restrict__ wk, const float* __restrict__ wv,
    unsigned short* __restrict__ xb, unsigned short* __restrict__ w3,
    float* __restrict__ lbuf, int nl) {
  const int nx4 = 16384 * 1024 / 4;
  const int nw4 = 1024 * 1024 / 4;
  const int total = nx4 + 3 * nw4;
  const int stride = gridDim.x * blockDim.x;
  const int tid = blockIdx.x * blockDim.x + threadIdx.x;
  for (int j = tid; j < total; j += stride) {
    if (j < nx4) {
      float4 v = ((const float4*)x)[j];
      ushort4 o; o.x = f2bf(v.x); o.y = f2bf(v.y); o.z = f2bf(v.z); o.w = f2bf(v.w);
      ((ushort4*)xb)[j] = o;
    } else {
      const int k = j - nx4;
      const float* src = k < nw4 ? wq : (k < 2 * nw4 ? wk : wv);
      const int so = k < nw4 ? k : (k < 2 * nw4 ? k - nw4 : k - 2 * nw4);
      float4 v = ((const float4*)src)[so];
      ushort4 o; o.x = f2bf(v.x); o.y = f2bf(v.y); o.z = f2bf(v.z); o.w = f2bf(v.w);
      ((ushort4*)w3)[k] = o;
    }
  }
  if (tid < nl) lbuf[tid] = 0.f;
}

// RoPE epilogue -> int8 (scale 32, clip +-127)
__device__ __forceinline__ void rope_store_i8(const f32x4 (&acc)[4][4],
                                              signed char* C,
                                              int rbase, int cbase) {
#pragma unroll
  for (int nj = 0; nj < 4; ++nj) {
    const int col = cbase + nj * 16;
    const float invfreq = exp2f(-0.025952563241307517f * (float)(col >> 1));
    const bool odd = (col & 1) != 0;
#pragma unroll
    for (int mi = 0; mi < 4; ++mi)
#pragma unroll
      for (int r = 0; r < 4; ++r) {
        const int row = rbase + mi * 16 + r;
        const float v = acc[mi][nj][r];
        const float p = __shfl_xor(v, 1, 64);
        const float ang = (float)(row & (SEQ - 1)) * invfreq;
        const float sn = __sinf(ang), cs = __cosf(ang);
        const float outv = odd ? (v * cs + p * sn) : (v * cs - p * sn);
        int q = (int)rintf(outv * 32.f);
        q = q > 127 ? 127 : (q < -127 ? -127 : q);
        C[(long)row * DIM + col] = (signed char)q;
      }
  }
}

// Fused Q+K projection (+RoPE, int8 out). 128x128 tile, BK=64, swizzled LDS.
__global__ __launch_bounds__(256, 2) void qk_proj_kernel(
    const unsigned short* __restrict__ X,
    const unsigned short* __restrict__ Wq,
    const unsigned short* __restrict__ Wk,
    signed char* __restrict__ Q,
    signed char* __restrict__ Ko) {
  const int bid = xcd_swz(blockIdx.x, gridDim.x);
  const int mt = bid >> 3, nt = bid & 7;
  const int m0 = mt * 128, n0 = nt * 128;

  __shared__ unsigned short sX[128 * 64];
  __shared__ unsigned short sQ[128 * 64];
  __shared__ unsigned short sK[128 * 64];

  const int t = threadIdx.x, w = t >> 6, l = t & 63;
  const int wm = w >> 1, wn = w & 1;
  const int srow = l >> 3;
  const int scol = ((l & 7) ^ srow) * 8;
  const int frow = l & 15;

  f32x4 cq[4][4] = {}, ck[4][4] = {};

  for (int k0 = 0; k0 < DIM; k0 += 64) {
#pragma unroll
    for (int j = 0; j < 4; ++j) {
      const int c = 4 * w + j;
      const int gr = c * 8 + srow;
      gll16(X  + (long)(m0 + gr) * DIM + k0 + scol, &sX[c * 512]);
      gll16(Wq + (long)(n0 + gr) * DIM + k0 + scol, &sQ[c * 512]);
      gll16(Wk + (long)(n0 + gr) * DIM + k0 + scol, &sK[c * 512]);
    }
    __syncthreads();
#pragma unroll
    for (int kk = 0; kk < 2; ++kk) {
      const int slot = (l >> 4) + 4 * kk;
      bf16x8 xa[4], bb[4];
#pragma unroll
      for (int i = 0; i < 4; ++i) {
        const int row = wm * 64 + i * 16 + frow;
        xa[i] = *(const bf16x8*)(&sX[row * 64 + ((slot ^ (row & 7)) << 3)]);
      }
#pragma unroll
      for (int i = 0; i < 4; ++i) {
        const int row = wn * 64 + i * 16 + frow;
        bb[i] = *(const bf16x8*)(&sQ[row * 64 + ((slot ^ (row & 7)) << 3)]);
      }
#pragma unroll
      for (int mi = 0; mi < 4; ++mi)
#pragma unroll
        for (int nj = 0; nj < 4; ++nj)
          cq[mi][nj] = __builtin_amdgcn_mfma_f32_16x16x32_bf16(xa[mi], bb[nj], cq[mi][nj], 0, 0, 0);
#pragma unroll
      for (int i = 0; i < 4; ++i) {
        const int row = wn * 64 + i * 16 + frow;
        bb[i] = *(const bf16x8*)(&sK[row * 64 + ((slot ^ (row & 7)) << 3)]);
      }
#pragma unroll
      for (int mi = 0; mi < 4; ++mi)
#pragma unroll
        for (int nj = 0; nj < 4; ++nj)
          ck[mi][nj] = __builtin_amdgcn_mfma_f32_16x16x32_bf16(xa[mi], bb[nj], ck[mi][nj], 0, 0, 0);
    }
    __syncthreads();
  }

  const int rbase = m0 + wm * 64 + (l >> 4) * 4;
  const int cbase = n0 + wn * 64 + frow;
  rope_store_i8(cq, Q, rbase, cbase);
  rope_store_i8(ck, Ko, rbase, cbase);
}

// V^T projection: VT[b][e][s]. [R2-verified, unchanged]
__global__ __launch_bounds__(256, 2) void vt_proj_kernel(
    const unsigned short* __restrict__ Wv,
    const unsigned short* __restrict__ X,
    unsigned short* __restrict__ VT) {
  const int bid = xcd_swz(blockIdx.x, gridDim.x);
  const int mt = bid >> 7, nt = bid & 127;
  const int m0 = mt * 128, n0 = nt * 128;

  __shared__ unsigned short sA[128 * 64];
  __shared__ unsigned short sB[128 * 64];

  const int t = threadIdx.x, w = t >> 6, l = t & 63;
  const int wm = w >> 1, wn = w & 1;
  const int srow = l >> 3;
  const int scol = ((l & 7) ^ srow) * 8;
  const int frow = l & 15;

  f32x4 acc[4][4] = {};

  for (int k0 = 0; k0 < DIM; k0 += 64) {
#pragma unroll
    for (int j = 0; j < 4; ++j) {
      const int c = 4 * w + j;
      const int gr = c * 8 + srow;
      gll16(Wv + (long)(m0 + gr) * DIM + k0 + scol, &sA[c * 512]);
      gll16(X  + (long)(n0 + gr) * DIM + k0 + scol, &sB[c * 512]);
    }
    __syncthreads();
#pragma unroll
    for (int kk = 0; kk < 2; ++kk) {
      const int slot = (l >> 4) + 4 * kk;
      bf16x8 av[4], bv[4];
#pragma unroll
      for (int i = 0; i < 4; ++i) {
        const int row = wm * 64 + i * 16 + frow;
        av[i] = *(const bf16x8*)(&sA[row * 64 + ((slot ^ (row & 7)) << 3)]);
      }
#pragma unroll
      for (int i = 0; i < 4; ++i) {
        const int row = wn * 64 + i * 16 + frow;
        bv[i] = *(const bf16x8*)(&sB[row * 64 + ((slot ^ (row & 7)) << 3)]);
      }
#pragma unroll
      for (int mi = 0; mi < 4; ++mi)
#pragma unroll
        for (int nj = 0; nj < 4; ++nj)
          acc[mi][nj] = __builtin_amdgcn_mfma_f32_16x16x32_bf16(av[mi], bv[nj], acc[mi][nj], 0, 0, 0);
    }
    __syncthreads();
  }

  const int rbase = m0 + wm * 64 + (l >> 4) * 4;
  const int cbase = n0 + wn * 64 + frow;
#pragma unroll
  for (int mi = 0; mi < 4; ++mi)
#pragma unroll
    for (int nj = 0; nj < 4; ++nj)
#pragma unroll
      for (int r = 0; r < 4; ++r) {
        const int row = rbase + mi * 16 + r;
        const int col = cbase + nj * 16;
        VT[(long)(col >> 12) * (DIM * SEQ) + (long)row * SEQ + (col & (SEQ - 1))] =
            f2bf(acc[mi][nj][r]);
      }
}

// INT8 scores -> P = exp(acc * 2^-15) bf16, packed triangular tiles, fused row-sum.
// [R14-verified, unchanged]
__global__ __launch_bounds__(256, 2) void sgemm_packed_kernel(
    const signed char* __restrict__ Q,
    const signed char* __restrict__ K,
    unsigned short* __restrict__ Pp,
    float* __restrict__ lbuf) {
  const int t0 = xcd_swz(blockIdx.x, gridDim.x);
  const int b = t0 / 528;
  const int t2 = t0 - b * 528;
  int i = (int)((sqrtf(8.f * (float)t2 + 1.f) - 1.f) * 0.5f);
  while ((i + 1) * (i + 2) / 2 <= t2) ++i;
  while (i * (i + 1) / 2 > t2) --i;
  const int j = t2 - i * (i + 1) / 2;

  const signed char* A = Q + ((long)b * SEQ + i * 128) * DIM;
  const signed char* B = K + ((long)b * SEQ + j * 128) * DIM;

  __shared__ signed char sA[128 * 128];
  __shared__ signed char sB[128 * 128];

  const int t = threadIdx.x, w = t >> 6, l = t & 63;
  const int wm = w >> 1, wn = w & 1;
  const int srow = l >> 3;
  const int sgc = ((l & 7) ^ srow) * 16;
  const int frow = l & 15;

  i32x4 acc[4][4] = {};

  for (int kt = 0; kt < 8; ++kt) {
#pragma unroll
    for (int jj = 0; jj < 4; ++jj) {
      const int c = 4 * w + jj;
      const int gr = c * 8 + srow;
      gll16(A + (long)gr * DIM + kt * 128 + sgc, &sA[c * 1024]);
      gll16(B + (long)gr * DIM + kt * 128 + sgc, &sB[c * 1024]);
    }
    __syncthreads();
#pragma unroll
    for (int kk = 0; kk < 2; ++kk) {
      const int slot = kk * 4 + (l >> 4);
      i32x4 av[4], bv[4];
#pragma unroll
      for (int ii = 0; ii < 4; ++ii) {
        const int row = wm * 64 + ii * 16 + frow;
        av[ii] = *(const i32x4*)(&sA[row * 128 + ((slot ^ (row & 7)) << 4)]);
      }
#pragma unroll
      for (int ii = 0; ii < 4; ++ii) {
        const int row = wn * 64 + ii * 16 + frow;
        bv[ii] = *(const i32x4*)(&sB[row * 128 + ((slot ^ (row & 7)) << 4)]);
      }
#pragma unroll
      for (int mi = 0; mi < 4; ++mi)
#pragma unroll
        for (int nj = 0; nj < 4; ++nj)
          acc[mi][nj] = __builtin_amdgcn_mfma_i32_16x16x64_i8(av[mi], bv[nj], acc[mi][nj], 0, 0, 0);
    }
    __syncthreads();
  }

  unsigned short* Ct = Pp + ((long)(b * 528 + t2) << 14);
  float* lrow = lbuf + (long)b * SEQ + i * 128;
  const int rb = wm * 64 + (l >> 4) * 4;
  const int cb = wn * 64 + frow;
  const bool diagt = (j == i);
  const float dq = 3.0517578125e-5f;      // 1/(32*32*32)

  float s[16];
#pragma unroll
  for (int mi = 0; mi < 4; ++mi)
#pragma unroll
    for (int r = 0; r < 4; ++r) {
      const int row = rb + mi * 16 + r;
      float rsum = 0.f;
#pragma unroll
      for (int nj = 0; nj < 4; ++nj) {
        const int col = cb + nj * 16;
        float p = __expf((float)acc[mi][nj][r] * dq);
        if (diagt && col > row) p = 0.f;
        Ct[row * 128 + col] = f2bf(p);
        rsum += p;
      }
      s[mi * 4 + r] = rsum;
    }

#pragma unroll
  for (int jj = 0; jj < 8; ++jj) {
    const float send = (frow & 8) ? s[jj] : s[jj + 8];
    const float got = __shfl_xor(send, 8, 64);
    s[jj] = ((frow & 8) ? s[jj + 8] : s[jj]) + got;
  }
#pragma unroll
  for (int jj = 0; jj < 4; ++jj) {
    const float send = (frow & 4) ? s[jj] : s[jj + 4];
    const float got = __shfl_xor(send, 4, 64);
    s[jj] = ((frow & 4) ? s[jj + 4] : s[jj]) + got;
  }
#pragma unroll
  for (int jj = 0; jj < 2; ++jj) {
    const float send = (frow & 2) ? s[jj] : s[jj + 2];
    const float got = __shfl_xor(send, 2, 64);
    s[jj] = ((frow & 2) ? s[jj + 2] : s[jj]) + got;
  }
  {
    const float send = (frow & 1) ? s[0] : s[1];
    const float got = __shfl_xor(send, 1, 64);
    s[0] = ((frow & 1) ? s[1] : s[0]) + got;
  }
  atomicAdd(&lrow[rb + (frow >> 2) * 16 + (frow & 3)], s[0]);
}

// PV, diagonal-paired, L2-resident V remap, BK=128 (one 32KB P-tile per barrier
// pair, 64 MFMA/step, half the barrier drains of R14).
__global__ __launch_bounds__(256, 2) void pv_kernel(
    const unsigned short* __restrict__ Pp,
    const unsigned short* __restrict__ VT,
    const float* __restrict__ lbuf,
    float* __restrict__ O,
    int nb) {
  const int work = xcd_swz(blockIdx.x, gridDim.x);
  int b, pr, d;
  if (nb == 4) {                     // grid 512: chunk(64) = {16 pr, b=x>>1, 4 d}
    const int x = work >> 6, wi = work & 63;
    b = x >> 1;
    pr = wi >> 2;
    d = ((x & 1) << 2) | (wi & 3);
  } else {                           // grid 128
    const int x = work >> 4, wi = work & 15;
    b = 0;
    pr = ((x >> 1) << 2) | (wi >> 2);
    d = ((x & 1) << 2) | (wi & 3);
  }
  const int n0 = d * 128;

  const unsigned short* Bp = VT + (long)b * DIM * SEQ + (long)n0 * SEQ;

  __shared__ unsigned short sA[128 * 128];   // P tile  [128 q][128 kv], swizzled
  __shared__ unsigned short sB[128 * 128];   // V chunk [128 d][128 kv], swizzled

  const int t = threadIdx.x, w = t >> 6, l = t & 63;
  const int wm = w >> 1, wn = w & 1;
  const int frow = l & 15;
  const int sr4 = l >> 4;            // staging row-in-4
  const int spos = l & 15;           // staging slot position

#pragma unroll
  for (int ph = 0; ph < 2; ++ph) {
    const int i = ph ? (31 - pr) : pr;
    const int m0 = i * 128;
    const unsigned short* At = Pp + ((long)(b * 528 + i * (i + 1) / 2) << 14);
    const float* lq = lbuf + (long)b * SEQ + m0;
    float* Op = O + ((long)b * SEQ + m0) * DIM;

    f32x4 acc[4][4] = {};

    for (int jt = 0; jt <= i; ++jt) {
      const unsigned short* Ak = At + ((long)jt << 14);
      const int k0 = jt * 128;
      // stage: 8 chunks/thread/matrix; chunk c = 4 rows of 256B; linear LDS dest,
      // pre-swizzled global src col (slot = spos ^ (row&7), 16B units)
#pragma unroll
      for (int j = 0; j < 8; ++j) {
        const int c = 8 * w + j;
        const int row = c * 4 + sr4;
        const int slot = spos ^ (row & 7);
        gll16(Ak + (long)row * 128 + slot * 8, &sA[c * 512]);
        gll16(Bp + (long)row * SEQ + k0 + slot * 8, &sB[c * 512]);
      }
      __syncthreads();
#pragma unroll
      for (int kk = 0; kk < 4; ++kk) {
        const int sl = (l >> 4) + 4 * kk;    // 0..15
        bf16x8 av[4], bv[4];
#pragma unroll
        for (int ii = 0; ii < 4; ++ii) {
          const int row = wm * 64 + ii * 16 + frow;
          av[ii] = *(const bf16x8*)(&sA[row * 128 + ((sl ^ (row & 7)) << 3)]);
        }
#pragma unroll
        for (int ii = 0; ii < 4; ++ii) {
          const int row = wn * 64 + ii * 16 + frow;
          bv[ii] = *(const bf16x8*)(&sB[row * 128 + ((sl ^ (row & 7)) << 3)]);
        }
#pragma unroll
        for (int mi = 0; mi < 4; ++mi)
#pragma unroll
          for (int nj = 0; nj < 4; ++nj)
            acc[mi][nj] = __builtin_amdgcn_mfma_f32_16x16x32_bf16(av[mi], bv[nj], acc[mi][nj], 0, 0, 0);
      }
      __syncthreads();
    }

    const int rb = wm * 64 + (l >> 4) * 4;
    const int cb = n0 + wn * 64 + frow;
#pragma unroll
    for (int mi = 0; mi < 4; ++mi)
#pragma unroll
      for (int r = 0; r < 4; ++r) {
        const int row = rb + mi * 16 + r;
        const float inv = 1.0f / lq[row];
#pragma unroll
        for (int nj = 0; nj < 4; ++nj)
          Op[(long)row * DIM + cb + nj * 16] = acc[mi][nj][r] * inv;
      }
  }
}

extern "C" void kernel_launch(void* const* d_in, const int* in_sizes, int n_in,
                              void* d_out, int out_size, void* d_ws, size_t ws_size,
                              hipStream_t stream) {
  (void)in_sizes; (void)n_in; (void)out_size;
  const float* x  = (const float*)d_in[0];
  const float* wq = (const float*)d_in[1];
  const float* wk = (const float*)d_in[2];
  const float* wv = (const float*)d_in[3];
  float* out = (float*)d_out;

  const long NTOK = (long)SEQ * 4;
  char* base = (char*)d_ws;
  unsigned short* xb = (unsigned short*)base;  base += NTOK * DIM * 2;
  signed char*    Qi = (signed char*)base;     base += NTOK * DIM;
  signed char*    Ki = (signed char*)base;     base += NTOK * DIM;
  unsigned short* VT = (unsigned short*)base;  base += NTOK * DIM * 2;
  unsigned short* w3 = (unsigned short*)base;
  unsigned short* wqb = w3;
  unsigned short* wkb = wqb + DIM * DIM;
  unsigned short* wvb = wkb + DIM * DIM;
  unsigned short* Pp  = w3;

  const size_t base_b = 4ull * NTOK * DIM * 2ull;
  const size_t full_need = base_b + (2112ull << 14) * 2 + 4ull * NTOK;
  const bool full = ws_size >= full_need;

  if (full) {
    float* lbuf = (float*)(Pp + (2112ull << 14));
    cvt_all_kernel<<<2048, 256, 0, stream>>>(x, wq, wk, wv, xb, w3, lbuf, (int)NTOK);
    qk_proj_kernel<<<128 * 8, 256, 0, stream>>>(xb, wqb, wkb, Qi, Ki);
    vt_proj_kernel<<<8 * 128, 256, 0, stream>>>(wvb, xb, VT);
    sgemm_packed_kernel<<<4 * 528, 256, 0, stream>>>(Qi, Ki, Pp, lbuf);
    pv_kernel<<<16 * 4 * 8, 256, 0, stream>>>(Pp, VT, lbuf, out, 4);
  } else {
    float* lbuf = (float*)(Pp + (528ull << 14));
    cvt_all_kernel<<<2048, 256, 0, stream>>>(x, wq, wk, wv, xb, w3, lbuf, 0);
    qk_proj_kernel<<<128 * 8, 256, 0, stream>>>(xb, wqb, wkb, Qi, Ki);
    vt_proj_kernel<<<8 * 128, 256, 0, stream>>>(wvb, xb, VT);
    for (int b = 0; b < 4; ++b) {
      hipMemsetAsync(lbuf, 0, SEQ * sizeof(float), stream);
      sgemm_packed_kernel<<<528, 256, 0, stream>>>(
          Qi + (long)b * SEQ * DIM, Ki + (long)b * SEQ * DIM, Pp, lbuf);
      pv_kernel<<<16 * 8, 256, 0, stream>>>(
          Pp, VT + (long)b * DIM * SEQ, lbuf, out + (long)b * SEQ * DIM, 1);
    }
  }
}

// Round 18
// 270.403 us; speedup vs baseline: 1.0115x; 1.0115x over previous
//
#include <hip/hip_runtime.h>
#include <hip/hip_bf16.h>

// SingleHeadAttention: B=4, S=4096, D=1024, fp32 in/out, causal, interleaved RoPE.
// R18: pv BK=128 kept, but LDS stored as TWO half-tiles [2][128][64] (the proven
//      0-conflict 128B-row geometry) -- R17's 256B-row swizzle measured 8.65M
//      bank conflicts (model wrong; reverting to verified layout). Single change.

#define SEQ 4096
#define DIM 1024

typedef short bf16x8 __attribute__((ext_vector_type(8)));
typedef float f32x4 __attribute__((ext_vector_type(4)));
typedef int i32x4 __attribute__((ext_vector_type(4)));

__device__ __forceinline__ unsigned short f2bf(float f) {
  unsigned int u = __float_as_uint(f);
  u += 0x7FFFu + ((u >> 16) & 1u);   // RNE
  return (unsigned short)(u >> 16);
}

// bijective XCD swizzle (grids % 8 == 0)
__device__ __forceinline__ int xcd_swz(int bid, int nwg) {
  return (bid & 7) * (nwg >> 3) + (bid >> 3);
}

__device__ __forceinline__ void gll16(const void* g, void* l) {
  __builtin_amdgcn_global_load_lds(
      (const __attribute__((address_space(1))) void*)g,
      (__attribute__((address_space(3))) void*)l, 16, 0, 0);
}

// fp32 -> bf16 for x and wq|wk|wv, plus lbuf zero-fill (one dispatch)
__global__ __launch_bounds__(256) void cvt_all_kernel(
    const float* __restrict__ x, const float* __restrict__ wq,
    const float* __restrict__ wk, const float* __restrict__ wv,
    unsigned short* __restrict__ xb, unsigned short* __restrict__ w3,
    float* __restrict__ lbuf, int nl) {
  const int nx4 = 16384 * 1024 / 4;
  const int nw4 = 1024 * 1024 / 4;
  const int total = nx4 + 3 * nw4;
  const int stride = gridDim.x * blockDim.x;
  const int tid = blockIdx.x * blockDim.x + threadIdx.x;
  for (int j = tid; j < total; j += stride) {
    if (j < nx4) {
      float4 v = ((const float4*)x)[j];
      ushort4 o; o.x = f2bf(v.x); o.y = f2bf(v.y); o.z = f2bf(v.z); o.w = f2bf(v.w);
      ((ushort4*)xb)[j] = o;
    } else {
      const int k = j - nx4;
      const float* src = k < nw4 ? wq : (k < 2 * nw4 ? wk : wv);
      const int so = k < nw4 ? k : (k < 2 * nw4 ? k - nw4 : k - 2 * nw4);
      float4 v = ((const float4*)src)[so];
      ushort4 o; o.x = f2bf(v.x); o.y = f2bf(v.y); o.z = f2bf(v.z); o.w = f2bf(v.w);
      ((ushort4*)w3)[k] = o;
    }
  }
  if (tid < nl) lbuf[tid] = 0.f;
}

// RoPE epilogue -> int8 (scale 32, clip +-127)
__device__ __forceinline__ void rope_store_i8(const f32x4 (&acc)[4][4],
                                              signed char* C,
                                              int rbase, int cbase) {
#pragma unroll
  for (int nj = 0; nj < 4; ++nj) {
    const int col = cbase + nj * 16;
    const float invfreq = exp2f(-0.025952563241307517f * (float)(col >> 1));
    const bool odd = (col & 1) != 0;
#pragma unroll
    for (int mi = 0; mi < 4; ++mi)
#pragma unroll
      for (int r = 0; r < 4; ++r) {
        const int row = rbase + mi * 16 + r;
        const float v = acc[mi][nj][r];
        const float p = __shfl_xor(v, 1, 64);
        const float ang = (float)(row & (SEQ - 1)) * invfreq;
        const float sn = __sinf(ang), cs = __cosf(ang);
        const float outv = odd ? (v * cs + p * sn) : (v * cs - p * sn);
        int q = (int)rintf(outv * 32.f);
        q = q > 127 ? 127 : (q < -127 ? -127 : q);
        C[(long)row * DIM + col] = (signed char)q;
      }
  }
}

// Fused Q+K projection (+RoPE, int8 out). 128x128 tile, BK=64, swizzled LDS.
__global__ __launch_bounds__(256, 2) void qk_proj_kernel(
    const unsigned short* __restrict__ X,
    const unsigned short* __restrict__ Wq,
    const unsigned short* __restrict__ Wk,
    signed char* __restrict__ Q,
    signed char* __restrict__ Ko) {
  const int bid = xcd_swz(blockIdx.x, gridDim.x);
  const int mt = bid >> 3, nt = bid & 7;
  const int m0 = mt * 128, n0 = nt * 128;

  __shared__ unsigned short sX[128 * 64];
  __shared__ unsigned short sQ[128 * 64];
  __shared__ unsigned short sK[128 * 64];

  const int t = threadIdx.x, w = t >> 6, l = t & 63;
  const int wm = w >> 1, wn = w & 1;
  const int srow = l >> 3;
  const int scol = ((l & 7) ^ srow) * 8;
  const int frow = l & 15;

  f32x4 cq[4][4] = {}, ck[4][4] = {};

  for (int k0 = 0; k0 < DIM; k0 += 64) {
#pragma unroll
    for (int j = 0; j < 4; ++j) {
      const int c = 4 * w + j;
      const int gr = c * 8 + srow;
      gll16(X  + (long)(m0 + gr) * DIM + k0 + scol, &sX[c * 512]);
      gll16(Wq + (long)(n0 + gr) * DIM + k0 + scol, &sQ[c * 512]);
      gll16(Wk + (long)(n0 + gr) * DIM + k0 + scol, &sK[c * 512]);
    }
    __syncthreads();
#pragma unroll
    for (int kk = 0; kk < 2; ++kk) {
      const int slot = (l >> 4) + 4 * kk;
      bf16x8 xa[4], bb[4];
#pragma unroll
      for (int i = 0; i < 4; ++i) {
        const int row = wm * 64 + i * 16 + frow;
        xa[i] = *(const bf16x8*)(&sX[row * 64 + ((slot ^ (row & 7)) << 3)]);
      }
#pragma unroll
      for (int i = 0; i < 4; ++i) {
        const int row = wn * 64 + i * 16 + frow;
        bb[i] = *(const bf16x8*)(&sQ[row * 64 + ((slot ^ (row & 7)) << 3)]);
      }
#pragma unroll
      for (int mi = 0; mi < 4; ++mi)
#pragma unroll
        for (int nj = 0; nj < 4; ++nj)
          cq[mi][nj] = __builtin_amdgcn_mfma_f32_16x16x32_bf16(xa[mi], bb[nj], cq[mi][nj], 0, 0, 0);
#pragma unroll
      for (int i = 0; i < 4; ++i) {
        const int row = wn * 64 + i * 16 + frow;
        bb[i] = *(const bf16x8*)(&sK[row * 64 + ((slot ^ (row & 7)) << 3)]);
      }
#pragma unroll
      for (int mi = 0; mi < 4; ++mi)
#pragma unroll
        for (int nj = 0; nj < 4; ++nj)
          ck[mi][nj] = __builtin_amdgcn_mfma_f32_16x16x32_bf16(xa[mi], bb[nj], ck[mi][nj], 0, 0, 0);
    }
    __syncthreads();
  }

  const int rbase = m0 + wm * 64 + (l >> 4) * 4;
  const int cbase = n0 + wn * 64 + frow;
  rope_store_i8(cq, Q, rbase, cbase);
  rope_store_i8(ck, Ko, rbase, cbase);
}

// V^T projection: VT[b][e][s]. [R2-verified, unchanged]
__global__ __launch_bounds__(256, 2) void vt_proj_kernel(
    const unsigned short* __restrict__ Wv,
    const unsigned short* __restrict__ X,
    unsigned short* __restrict__ VT) {
  const int bid = xcd_swz(blockIdx.x, gridDim.x);
  const int mt = bid >> 7, nt = bid & 127;
  const int m0 = mt * 128, n0 = nt * 128;

  __shared__ unsigned short sA[128 * 64];
  __shared__ unsigned short sB[128 * 64];

  const int t = threadIdx.x, w = t >> 6, l = t & 63;
  const int wm = w >> 1, wn = w & 1;
  const int srow = l >> 3;
  const int scol = ((l & 7) ^ srow) * 8;
  const int frow = l & 15;

  f32x4 acc[4][4] = {};

  for (int k0 = 0; k0 < DIM; k0 += 64) {
#pragma unroll
    for (int j = 0; j < 4; ++j) {
      const int c = 4 * w + j;
      const int gr = c * 8 + srow;
      gll16(Wv + (long)(m0 + gr) * DIM + k0 + scol, &sA[c * 512]);
      gll16(X  + (long)(n0 + gr) * DIM + k0 + scol, &sB[c * 512]);
    }
    __syncthreads();
#pragma unroll
    for (int kk = 0; kk < 2; ++kk) {
      const int slot = (l >> 4) + 4 * kk;
      bf16x8 av[4], bv[4];
#pragma unroll
      for (int i = 0; i < 4; ++i) {
        const int row = wm * 64 + i * 16 + frow;
        av[i] = *(const bf16x8*)(&sA[row * 64 + ((slot ^ (row & 7)) << 3)]);
      }
#pragma unroll
      for (int i = 0; i < 4; ++i) {
        const int row = wn * 64 + i * 16 + frow;
        bv[i] = *(const bf16x8*)(&sB[row * 64 + ((slot ^ (row & 7)) << 3)]);
      }
#pragma unroll
      for (int mi = 0; mi < 4; ++mi)
#pragma unroll
        for (int nj = 0; nj < 4; ++nj)
          acc[mi][nj] = __builtin_amdgcn_mfma_f32_16x16x32_bf16(av[mi], bv[nj], acc[mi][nj], 0, 0, 0);
    }
    __syncthreads();
  }

  const int rbase = m0 + wm * 64 + (l >> 4) * 4;
  const int cbase = n0 + wn * 64 + frow;
#pragma unroll
  for (int mi = 0; mi < 4; ++mi)
#pragma unroll
    for (int nj = 0; nj < 4; ++nj)
#pragma unroll
      for (int r = 0; r < 4; ++r) {
        const int row = rbase + mi * 16 + r;
        const int col = cbase + nj * 16;
        VT[(long)(col >> 12) * (DIM * SEQ) + (long)row * SEQ + (col & (SEQ - 1))] =
            f2bf(acc[mi][nj][r]);
      }
}

// INT8 scores -> P = exp(acc * 2^-15) bf16, packed triangular tiles, fused row-sum.
// [R14-verified, unchanged]
__global__ __launch_bounds__(256, 2) void sgemm_packed_kernel(
    const signed char* __restrict__ Q,
    const signed char* __restrict__ K,
    unsigned short* __restrict__ Pp,
    float* __restrict__ lbuf) {
  const int t0 = xcd_swz(blockIdx.x, gridDim.x);
  const int b = t0 / 528;
  const int t2 = t0 - b * 528;
  int i = (int)((sqrtf(8.f * (float)t2 + 1.f) - 1.f) * 0.5f);
  while ((i + 1) * (i + 2) / 2 <= t2) ++i;
  while (i * (i + 1) / 2 > t2) --i;
  const int j = t2 - i * (i + 1) / 2;

  const signed char* A = Q + ((long)b * SEQ + i * 128) * DIM;
  const signed char* B = K + ((long)b * SEQ + j * 128) * DIM;

  __shared__ signed char sA[128 * 128];
  __shared__ signed char sB[128 * 128];

  const int t = threadIdx.x, w = t >> 6, l = t & 63;
  const int wm = w >> 1, wn = w & 1;
  const int srow = l >> 3;
  const int sgc = ((l & 7) ^ srow) * 16;
  const int frow = l & 15;

  i32x4 acc[4][4] = {};

  for (int kt = 0; kt < 8; ++kt) {
#pragma unroll
    for (int jj = 0; jj < 4; ++jj) {
      const int c = 4 * w + jj;
      const int gr = c * 8 + srow;
      gll16(A + (long)gr * DIM + kt * 128 + sgc, &sA[c * 1024]);
      gll16(B + (long)gr * DIM + kt * 128 + sgc, &sB[c * 1024]);
    }
    __syncthreads();
#pragma unroll
    for (int kk = 0; kk < 2; ++kk) {
      const int slot = kk * 4 + (l >> 4);
      i32x4 av[4], bv[4];
#pragma unroll
      for (int ii = 0; ii < 4; ++ii) {
        const int row = wm * 64 + ii * 16 + frow;
        av[ii] = *(const i32x4*)(&sA[row * 128 + ((slot ^ (row & 7)) << 4)]);
      }
#pragma unroll
      for (int ii = 0; ii < 4; ++ii) {
        const int row = wn * 64 + ii * 16 + frow;
        bv[ii] = *(const i32x4*)(&sB[row * 128 + ((slot ^ (row & 7)) << 4)]);
      }
#pragma unroll
      for (int mi = 0; mi < 4; ++mi)
#pragma unroll
        for (int nj = 0; nj < 4; ++nj)
          acc[mi][nj] = __builtin_amdgcn_mfma_i32_16x16x64_i8(av[mi], bv[nj], acc[mi][nj], 0, 0, 0);
    }
    __syncthreads();
  }

  unsigned short* Ct = Pp + ((long)(b * 528 + t2) << 14);
  float* lrow = lbuf + (long)b * SEQ + i * 128;
  const int rb = wm * 64 + (l >> 4) * 4;
  const int cb = wn * 64 + frow;
  const bool diagt = (j == i);
  const float dq = 3.0517578125e-5f;      // 1/(32*32*32)

  float s[16];
#pragma unroll
  for (int mi = 0; mi < 4; ++mi)
#pragma unroll
    for (int r = 0; r < 4; ++r) {
      const int row = rb + mi * 16 + r;
      float rsum = 0.f;
#pragma unroll
      for (int nj = 0; nj < 4; ++nj) {
        const int col = cb + nj * 16;
        float p = __expf((float)acc[mi][nj][r] * dq);
        if (diagt && col > row) p = 0.f;
        Ct[row * 128 + col] = f2bf(p);
        rsum += p;
      }
      s[mi * 4 + r] = rsum;
    }

#pragma unroll
  for (int jj = 0; jj < 8; ++jj) {
    const float send = (frow & 8) ? s[jj] : s[jj + 8];
    const float got = __shfl_xor(send, 8, 64);
    s[jj] = ((frow & 8) ? s[jj + 8] : s[jj]) + got;
  }
#pragma unroll
  for (int jj = 0; jj < 4; ++jj) {
    const float send = (frow & 4) ? s[jj] : s[jj + 4];
    const float got = __shfl_xor(send, 4, 64);
    s[jj] = ((frow & 4) ? s[jj + 4] : s[jj]) + got;
  }
#pragma unroll
  for (int jj = 0; jj < 2; ++jj) {
    const float send = (frow & 2) ? s[jj] : s[jj + 2];
    const float got = __shfl_xor(send, 2, 64);
    s[jj] = ((frow & 2) ? s[jj + 2] : s[jj]) + got;
  }
  {
    const float send = (frow & 1) ? s[0] : s[1];
    const float got = __shfl_xor(send, 1, 64);
    s[0] = ((frow & 1) ? s[1] : s[0]) + got;
  }
  atomicAdd(&lrow[rb + (frow >> 2) * 16 + (frow & 3)], s[0]);
}

// PV, diagonal-paired, L2-resident V remap, BK=128 staged as [2][128][64]
// half-tiles (proven 0-conflict 128B-row geometry).
__global__ __launch_bounds__(256, 2) void pv_kernel(
    const unsigned short* __restrict__ Pp,
    const unsigned short* __restrict__ VT,
    const float* __restrict__ lbuf,
    float* __restrict__ O,
    int nb) {
  const int work = xcd_swz(blockIdx.x, gridDim.x);
  int b, pr, d;
  if (nb == 4) {                     // grid 512: chunk(64) = {16 pr, b=x>>1, 4 d}
    const int x = work >> 6, wi = work & 63;
    b = x >> 1;
    pr = wi >> 2;
    d = ((x & 1) << 2) | (wi & 3);
  } else {                           // grid 128
    const int x = work >> 4, wi = work & 15;
    b = 0;
    pr = ((x >> 1) << 2) | (wi >> 2);
    d = ((x & 1) << 2) | (wi & 3);
  }
  const int n0 = d * 128;

  const unsigned short* Bp = VT + (long)b * DIM * SEQ + (long)n0 * SEQ;

  __shared__ unsigned short sA[2 * 128 * 64];   // [kv-half][128 q][64 kv] swizzled
  __shared__ unsigned short sB[2 * 128 * 64];   // [kv-half][128 d][64 kv] swizzled

  const int t = threadIdx.x, w = t >> 6, l = t & 63;
  const int wm = w >> 1, wn = w & 1;
  const int frow = l & 15;
  const int cr8 = l >> 3;            // staging row-in-8
  const int cp8 = l & 7;             // staging slot position (8 per 128B row)

#pragma unroll
  for (int ph = 0; ph < 2; ++ph) {
    const int i = ph ? (31 - pr) : pr;
    const int m0 = i * 128;
    const unsigned short* At = Pp + ((long)(b * 528 + i * (i + 1) / 2) << 14);
    const float* lq = lbuf + (long)b * SEQ + m0;
    float* Op = O + ((long)b * SEQ + m0) * DIM;

    f32x4 acc[4][4] = {};

    for (int jt = 0; jt <= i; ++jt) {
      const unsigned short* Ak = At + ((long)jt << 14);
      const int k0 = jt * 128;
      // stage both halves: chunk c in 0..31; h = c>>4, rows 8*(c&15)..+7;
      // lane l -> row offset l>>3, slot pos l&7; global slot g = h*8 + (pos^(row&7))
#pragma unroll
      for (int j = 0; j < 8; ++j) {
        const int c = 8 * w + j;
        const int h = c >> 4;
        const int row = (c & 15) * 8 + cr8;
        const int g = h * 8 + (cp8 ^ (row & 7));
        gll16(Ak + (long)row * 128 + g * 8, &sA[c * 512]);
        gll16(Bp + (long)row * SEQ + k0 + g * 8, &sB[c * 512]);
      }
      __syncthreads();
#pragma unroll
      for (int kk = 0; kk < 4; ++kk) {
        const int sl = (l >> 4) + 4 * kk;    // global slot 0..15
        const int h = sl >> 3, g8 = sl & 7;
        const int hb = h * 8192;
        bf16x8 av[4], bv[4];
#pragma unroll
        for (int ii = 0; ii < 4; ++ii) {
          const int row = wm * 64 + ii * 16 + frow;
          av[ii] = *(const bf16x8*)(&sA[hb + row * 64 + ((g8 ^ (row & 7)) << 3)]);
        }
#pragma unroll
        for (int ii = 0; ii < 4; ++ii) {
          const int row = wn * 64 + ii * 16 + frow;
          bv[ii] = *(const bf16x8*)(&sB[hb + row * 64 + ((g8 ^ (row & 7)) << 3)]);
        }
#pragma unroll
        for (int mi = 0; mi < 4; ++mi)
#pragma unroll
          for (int nj = 0; nj < 4; ++nj)
            acc[mi][nj] = __builtin_amdgcn_mfma_f32_16x16x32_bf16(av[mi], bv[nj], acc[mi][nj], 0, 0, 0);
      }
      __syncthreads();
    }

    const int rb = wm * 64 + (l >> 4) * 4;
    const int cb = n0 + wn * 64 + frow;
#pragma unroll
    for (int mi = 0; mi < 4; ++mi)
#pragma unroll
      for (int r = 0; r < 4; ++r) {
        const int row = rb + mi * 16 + r;
        const float inv = 1.0f / lq[row];
#pragma unroll
        for (int nj = 0; nj < 4; ++nj)
          Op[(long)row * DIM + cb + nj * 16] = acc[mi][nj][r] * inv;
      }
  }
}

extern "C" void kernel_launch(void* const* d_in, const int* in_sizes, int n_in,
                              void* d_out, int out_size, void* d_ws, size_t ws_size,
                              hipStream_t stream) {
  (void)in_sizes; (void)n_in; (void)out_size;
  const float* x  = (const float*)d_in[0];
  const float* wq = (const float*)d_in[1];
  const float* wk = (const float*)d_in[2];
  const float* wv = (const float*)d_in[3];
  float* out = (float*)d_out;

  const long NTOK = (long)SEQ * 4;
  char* base = (char*)d_ws;
  unsigned short* xb = (unsigned short*)base;  base += NTOK * DIM * 2;
  signed char*    Qi = (signed char*)base;     base += NTOK * DIM;
  signed char*    Ki = (signed char*)base;     base += NTOK * DIM;
  unsigned short* VT = (unsigned short*)base;  base += NTOK * DIM * 2;
  unsigned short* w3 = (unsigned short*)base;
  unsigned short* wqb = w3;
  unsigned short* wkb = wqb + DIM * DIM;
  unsigned short* wvb = wkb + DIM * DIM;
  unsigned short* Pp  = w3;

  const size_t base_b = 4ull * NTOK * DIM * 2ull;
  const size_t full_need = base_b + (2112ull << 14) * 2 + 4ull * NTOK;
  const bool full = ws_size >= full_need;

  if (full) {
    float* lbuf = (float*)(Pp + (2112ull << 14));
    cvt_all_kernel<<<2048, 256, 0, stream>>>(x, wq, wk, wv, xb, w3, lbuf, (int)NTOK);
    qk_proj_kernel<<<128 * 8, 256, 0, stream>>>(xb, wqb, wkb, Qi, Ki);
    vt_proj_kernel<<<8 * 128, 256, 0, stream>>>(wvb, xb, VT);
    sgemm_packed_kernel<<<4 * 528, 256, 0, stream>>>(Qi, Ki, Pp, lbuf);
    pv_kernel<<<16 * 4 * 8, 256, 0, stream>>>(Pp, VT, lbuf, out, 4);
  } else {
    float* lbuf = (float*)(Pp + (528ull << 14));
    cvt_all_kernel<<<2048, 256, 0, stream>>>(x, wq, wk, wv, xb, w3, lbuf, 0);
    qk_proj_kernel<<<128 * 8, 256, 0, stream>>>(xb, wqb, wkb, Qi, Ki);
    vt_proj_kernel<<<8 * 128, 256, 0, stream>>>(wvb, xb, VT);
    for (int b = 0; b < 4; ++b) {
      hipMemsetAsync(lbuf, 0, SEQ * sizeof(float), stream);
      sgemm_packed_kernel<<<528, 256, 0, stream>>>(
          Qi + (long)b * SEQ * DIM, Ki + (long)b * SEQ * DIM, Pp, lbuf);
      pv_kernel<<<16 * 8, 256, 0, stream>>>(
          Pp, VT + (long)b * DIM * SEQ, lbuf, out + (long)b * SEQ * DIM, 1);
    }
  }
}